// Round 3
// baseline (812.047 us; speedup 1.0000x reference)
//
#include <hip/hip_runtime.h>
#include <hip/hip_bf16.h>

typedef __attribute__((ext_vector_type(8))) short short8;
typedef __attribute__((ext_vector_type(16))) float f32x16;

union U8 { short8 s; unsigned int u[4]; };

static __device__ __forceinline__ unsigned short f2bf(float f) {
  unsigned int u = __float_as_uint(f);
  u += 0x7fffu + ((u >> 16) & 1u);
  return (unsigned short)(u >> 16);
}
// v_cvt_pk_bf16_f32: low half = bf16(lo), high half = bf16(hi), RNE
static __device__ __forceinline__ unsigned int cvtpk(float lo, float hi) {
  unsigned int r;
  asm("v_cvt_pk_bf16_f32 %0, %1, %2" : "=v"(r) : "v"(lo), "v"(hi));
  return r;
}
static __device__ __forceinline__ f32x16 MFMA(short8 a, short8 b, f32x16 c) {
  return __builtin_amdgcn_mfma_f32_32x32x16_bf16(a, b, c, 0, 0, 0);
}

// ---------------------------------------------------------------------------
// prep: convert weights to bf16 (w1 padded to K=16) into workspace
// ---------------------------------------------------------------------------
__global__ void prep_weights(const float* __restrict__ w1, const float* __restrict__ w2,
                             const float* __restrict__ w3,
                             unsigned short* __restrict__ w1p, unsigned short* __restrict__ w2b,
                             unsigned short* __restrict__ w3b) {
  int i = blockIdx.x * 256 + threadIdx.x;
  if (i < 512) { int c = i >> 4, k = i & 15; w1p[i] = (k < 6) ? f2bf(w1[c * 6 + k]) : (unsigned short)0; }
  if (i < 4096) w2b[i] = f2bf(w2[i]);
  if (i < 32768) w3b[i] = f2bf(w3[i]);
}

// ---------------------------------------------------------------------------
// Fused per-point MLP (6->32->128->256, bf16 MFMA) + segment-max.
// 4 waves/block, each wave owns 256 contiguous points = 8 subtiles of 32.
// Per subtile: L1/L2 as D = W.X^T (col=point), h2 transposed via per-wave LDS
// (8KB, XOR-swizzled), L3 as D = h2.w3^T (col=channel) so segment-max is an
// in-lane 16-reg max + one shfl_xor(32) merge. Running per-segment max in
// regs; atomicMax(int) only at segment transitions, filtered by v>0
// (xmax pre-zeroed => non-positive maxima are no-ops).
// LDS 40KB/block -> 4 blocks/CU; launch_bounds targets 4 waves/SIMD.
// ---------------------------------------------------------------------------
__global__ __launch_bounds__(256, 4) void mlp_segmax_mfma(
    const float* __restrict__ points, const float* __restrict__ color,
    const int* __restrict__ batch,
    const unsigned short* __restrict__ w1p, const unsigned short* __restrict__ w2b,
    const unsigned short* __restrict__ w3b,
    const float* __restrict__ b1, const float* __restrict__ b2, const float* __restrict__ b3,
    float* __restrict__ xmax, int N)
{
  __shared__ __align__(16) char smem[40960];   // 4 waves x (8KB h2 + 2KB h1)
  const int tid  = threadIdx.x;
  const int wv   = tid >> 6;
  const int lane = tid & 63;
  const int g    = lane >> 5;
  const int l31  = lane & 31;
  char* h2base = smem + wv * 8192;
  char* h1base = smem + 32768 + wv * 2048;

  // ---- bias preloads (channel map of 32x32 C/D: ch(r) = (r&3)+8*(r>>2)+4g) ----
  unsigned int b1pk[8];
#pragma unroll
  for (int rr = 0; rr < 8; ++rr) {
    int r = 2 * rr, ch = (r & 3) + 8 * (r >> 2) + 4 * g;
    b1pk[rr] = (unsigned)f2bf(b1[ch]) | ((unsigned)f2bf(b1[ch + 1]) << 16);
  }
  unsigned int b2pk[32];
#pragma unroll
  for (int t2 = 0; t2 < 4; ++t2)
#pragma unroll
    for (int q = 0; q < 4; ++q)
#pragma unroll
      for (int h = 0; h < 2; ++h) {
        int ch = 32 * t2 + 8 * q + 4 * g + 2 * h;
        b2pk[t2 * 8 + q * 2 + h] = (unsigned)f2bf(b2[ch]) | ((unsigned)f2bf(b2[ch + 1]) << 16);
      }
  float b3v[8];
#pragma unroll
  for (int t = 0; t < 8; ++t) b3v[t] = b3[32 * t + l31];

  // w1 fragment is tiny and constant: keep in regs across all iterations
  const short8 a1 = *reinterpret_cast<const short8*>(w1p + l31 * 16 + 8 * g);

  const int wid = blockIdx.x * 4 + wv;
  int cur = -1;
  float rmax[8];
#pragma unroll
  for (int t = 0; t < 8; ++t) rmax[t] = -INFINITY;

  auto flush = [&]() {
    if (cur < 0) return;
#pragma unroll
    for (int t = 0; t < 8; ++t) {
      float v = fmaxf(rmax[t], __shfl_xor(rmax[t], 32));
      if (lane < 32 && v > 0.0f)
        atomicMax((int*)xmax + cur * 256 + 32 * t + lane, __float_as_int(v));
    }
  };

  // ---- input prefetch for subtile 0 ----
  const long long wbase = (long long)wid * 256;
  float n0 = 0, n1 = 0, n2 = 0, n3 = 0, n4 = 0, n5 = 0;
  int nseg = -2 - lane;
  if (wbase < (long long)N) {
    const int p = (int)wbase + l31;
    n0 = points[p * 3 + 0]; n1 = points[p * 3 + 1]; n2 = points[p * 3 + 2];
    n3 = color[p * 3 + 0];  n4 = color[p * 3 + 1];  n5 = color[p * 3 + 2];
    nseg = batch[p];
  }

  for (int it = 0; it < 8; ++it) {
    const long long base = wbase + (long long)it * 32;
    if (base >= (long long)N) break;   // N % 32 == 0 for this problem

    const float c0 = n0, c1 = n1, c2 = n2, c3 = n3, c4 = n4, c5 = n5;
    const int segv = nseg;

    // issue next subtile's loads now; they complete under this subtile's MFMAs
    if (base + 32 < (long long)N && it < 7) {
      const int p = (int)base + 32 + l31;
      n0 = points[p * 3 + 0]; n1 = points[p * 3 + 1]; n2 = points[p * 3 + 2];
      n3 = color[p * 3 + 0];  n4 = color[p * 3 + 1];  n5 = color[p * 3 + 2];
      nseg = batch[p];
    }

    // opaque pointer copies: defeat LICM hoisting weight fragments across iters
    unsigned long long a2p = (unsigned long long)w2b; asm volatile("" : "+s"(a2p));
    unsigned long long a3p = (unsigned long long)w3b; asm volatile("" : "+s"(a3p));
    const unsigned short* w2l = (const unsigned short*)a2p;
    const unsigned short* w3l = (const unsigned short*)a3p;

    // ---------------- layer 1 (6->32) ----------------
    const unsigned int zm = (g == 0) ? 0xffffffffu : 0u;  // g=1 supplies K-pad
    U8 bin;
    bin.u[0] = cvtpk(c0, c1) & zm;
    bin.u[1] = cvtpk(c2, c3) & zm;
    bin.u[2] = cvtpk(c4, c5) & zm;
    bin.u[3] = 0;
    f32x16 ci;
#pragma unroll
    for (int rr = 0; rr < 8; ++rr) {
      ci[2 * rr + 0] = __uint_as_float(b1pk[rr] << 16);
      ci[2 * rr + 1] = __uint_as_float(b1pk[rr] & 0xffff0000u);
    }
    f32x16 d1 = MFMA(a1, bin.s, ci);            // D[ch][pt], col=pt
    // h1 -> LDS (row=point, 64B rows, slot-XOR (row&3))
#pragma unroll
    for (int q = 0; q < 4; ++q) {
      float f0 = fmaxf(d1[q * 4 + 0], 0.f), f1 = fmaxf(d1[q * 4 + 1], 0.f);
      float f2 = fmaxf(d1[q * 4 + 2], 0.f), f3 = fmaxf(d1[q * 4 + 3], 0.f);
      uint2 w; w.x = cvtpk(f0, f1); w.y = cvtpk(f2, f3);
      *reinterpret_cast<uint2*>(h1base + l31 * 64 + ((q ^ (l31 & 3)) << 4) + 8 * g) = w;
    }
    const short8 h1f0 = *reinterpret_cast<const short8*>(h1base + l31 * 64 + (((0 + g) ^ (l31 & 3)) << 4));
    const short8 h1f1 = *reinterpret_cast<const short8*>(h1base + l31 * 64 + (((2 + g) ^ (l31 & 3)) << 4));

    // ---------------- layer 2 (32->128) ----------------
#pragma unroll
    for (int t2 = 0; t2 < 4; ++t2) {
      f32x16 cc;
#pragma unroll
      for (int q = 0; q < 4; ++q) {
        unsigned int pka = b2pk[t2 * 8 + q * 2 + 0], pkb = b2pk[t2 * 8 + q * 2 + 1];
        cc[q * 4 + 0] = __uint_as_float(pka << 16);
        cc[q * 4 + 1] = __uint_as_float(pka & 0xffff0000u);
        cc[q * 4 + 2] = __uint_as_float(pkb << 16);
        cc[q * 4 + 3] = __uint_as_float(pkb & 0xffff0000u);
      }
      short8 a20 = *reinterpret_cast<const short8*>(w2l + (l31 + 32 * t2) * 32 + 8 * g);
      short8 a21 = *reinterpret_cast<const short8*>(w2l + (l31 + 32 * t2) * 32 + 16 + 8 * g);
      f32x16 d2 = MFMA(a20, h1f0, cc);
      d2 = MFMA(a21, h1f1, d2);                 // D[ch][pt], col=pt
      // relu + bf16 pack -> h2 LDS (row=point, 256B rows, slot-XOR (row&15))
#pragma unroll
      for (int q = 0; q < 4; ++q) {
        float f0 = fmaxf(d2[q * 4 + 0], 0.f), f1 = fmaxf(d2[q * 4 + 1], 0.f);
        float f2 = fmaxf(d2[q * 4 + 2], 0.f), f3 = fmaxf(d2[q * 4 + 3], 0.f);
        uint2 w; w.x = cvtpk(f0, f1); w.y = cvtpk(f2, f3);
        int slot = q + 4 * t2;
        *reinterpret_cast<uint2*>(h2base + l31 * 256 + ((slot ^ (l31 & 15)) << 4) + 8 * g) = w;
      }
    }

    // ---------------- A3 fragments ----------------
    short8 a3[8];
#pragma unroll
    for (int k0 = 0; k0 < 8; ++k0)
      a3[k0] = *reinterpret_cast<const short8*>(
          h2base + l31 * 256 + (((2 * k0 + g) ^ (l31 & 15)) << 4));

    // ---------------- segment bookkeeping ----------------
    const int segA = __builtin_amdgcn_readfirstlane(segv);
    const int segD = __shfl(segv, 31);
    const bool caseU = (segA == segD);
    if (segA != cur) {
      flush();
#pragma unroll
      for (int t = 0; t < 8; ++t) rmax[t] = -INFINITY;
      cur = segA;
    }
    unsigned int bA = 0, bD = 0;
    bool restAny = false;
    if (!caseU) {
      bA = (unsigned int)__ballot(segv == segA);
      bD = (unsigned int)__ballot(segv == segD);
      restAny = ((bA | bD) != 0xffffffffu);
    }

    // ---------------- layer 3 (128->256): D = h2 . w3^T, col=channel ----------------
#pragma unroll
    for (int t = 0; t < 8; ++t) {
      f32x16 acc;
#pragma unroll
      for (int r = 0; r < 16; ++r) acc[r] = b3v[t];
#pragma unroll
      for (int hh = 0; hh < 2; ++hh) {
        short8 bf[4];
#pragma unroll
        for (int k = 0; k < 4; ++k)
          bf[k] = *reinterpret_cast<const short8*>(
              w3l + (l31 + 32 * t) * 128 + (4 * hh + k) * 16 + 8 * g);
#pragma unroll
        for (int k = 0; k < 4; ++k) acc = MFMA(a3[4 * hh + k], bf[k], acc);
      }
      if (caseU) {
        float m = acc[0];
#pragma unroll
        for (int r = 1; r < 16; ++r) m = fmaxf(m, acc[r]);
        rmax[t] = fmaxf(rmax[t], m);
      } else {
        float ma = -INFINITY, md = -INFINITY;
#pragma unroll
        for (int r = 0; r < 16; ++r) {
          const int idx = (r & 3) + 8 * (r >> 2) + 4 * g;
          const unsigned int bit = 1u << idx;
          const float v = acc[r];
          ma = fmaxf(ma, (bA & bit) ? v : -INFINITY);
          md = fmaxf(md, (bD & bit) ? v : -INFINITY);
        }
        if (restAny) {   // >2 segments inside one 32-pt subtile: rare slow path
#pragma unroll
          for (int r = 0; r < 16; ++r) {
            const int idx = (r & 3) + 8 * (r >> 2) + 4 * g;
            const unsigned int bit = 1u << idx;
            if (!((bA | bD) & bit)) {
              const int sid = __shfl(segv, idx);
              const float v = acc[r];
              if (sid >= 0 && v > 0.0f)
                atomicMax((int*)xmax + sid * 256 + 32 * t + l31, __float_as_int(v));
            }
          }
        }
        // close segA for this channel group right here (no extra arrays)
        float va = fmaxf(rmax[t], ma);
        va = fmaxf(va, __shfl_xor(va, 32));
        if (lane < 32 && va > 0.0f)
          atomicMax((int*)xmax + segA * 256 + 32 * t + l31, __float_as_int(va));
        rmax[t] = md;    // start accumulating segD
      }
    }
    if (!caseU) cur = segD;
  }
  flush();
}

// ---------------------------------------------------------------------------
// FC head  [B,256] -> 128 -> 64 -> 75, + coef scale/shift (unchanged)
// ---------------------------------------------------------------------------
__global__ __launch_bounds__(256) void head_kernel(
    const float* __restrict__ xmax,
    const float* __restrict__ fw1, const float* __restrict__ fb1,
    const float* __restrict__ fw2, const float* __restrict__ fb2,
    const float* __restrict__ fw3, const float* __restrict__ fb3,
    const float* __restrict__ cmean, const float* __restrict__ cstd,
    float* __restrict__ out, int B)
{
  __shared__ __align__(16) float xm[16][260];
  __shared__ __align__(16) float h1b[16][132];
  __shared__ __align__(16) float h2b[16][68];

  const int t = threadIdx.x;
  const int bbase = blockIdx.x * 16;

  for (int i = t; i < 16 * 256; i += 256) {
    const int bi = i >> 8, k = i & 255;
    const int bb = min(bbase + bi, B - 1);
    xm[bi][k] = xmax[(long long)bb * 256 + k];
  }
  __syncthreads();

  {
    const int bi = t >> 4, oi = t & 15;
    float acc[8];
#pragma unroll
    for (int u = 0; u < 8; ++u) acc[u] = fb1[oi * 8 + u];
    for (int k = 0; k < 256; k += 4) {
      const float4 xv = *reinterpret_cast<const float4*>(&xm[bi][k]);
#pragma unroll
      for (int u = 0; u < 8; ++u) {
        const float4 wv = *reinterpret_cast<const float4*>(fw1 + (oi * 8 + u) * 256 + k);
        acc[u] = fmaf(xv.x, wv.x, acc[u]);
        acc[u] = fmaf(xv.y, wv.y, acc[u]);
        acc[u] = fmaf(xv.z, wv.z, acc[u]);
        acc[u] = fmaf(xv.w, wv.w, acc[u]);
      }
    }
#pragma unroll
    for (int u = 0; u < 8; ++u) h1b[bi][oi * 8 + u] = fmaxf(acc[u], 0.0f);
  }
  __syncthreads();

  {
    const int bi = t >> 4, oi = t & 15;
    float acc[4];
#pragma unroll
    for (int u = 0; u < 4; ++u) acc[u] = fb2[oi * 4 + u];
    for (int k = 0; k < 128; k += 4) {
      const float4 xv = *reinterpret_cast<const float4*>(&h1b[bi][k]);
#pragma unroll
      for (int u = 0; u < 4; ++u) {
        const float4 wv = *reinterpret_cast<const float4*>(fw2 + (oi * 4 + u) * 128 + k);
        acc[u] = fmaf(xv.x, wv.x, acc[u]);
        acc[u] = fmaf(xv.y, wv.y, acc[u]);
        acc[u] = fmaf(xv.z, wv.z, acc[u]);
        acc[u] = fmaf(xv.w, wv.w, acc[u]);
      }
    }
#pragma unroll
    for (int u = 0; u < 4; ++u) h2b[bi][oi * 4 + u] = fmaxf(acc[u], 0.0f);
  }
  __syncthreads();

  for (int i = t; i < 16 * 75; i += 256) {
    const int bi = i / 75, o = i - bi * 75;
    float a = fb3[o];
    for (int k = 0; k < 64; k += 4) {
      const float4 xv = *reinterpret_cast<const float4*>(&h2b[bi][k]);
      const float4 wv = *reinterpret_cast<const float4*>(fw3 + o * 64 + k);
      a = fmaf(xv.x, wv.x, a);
      a = fmaf(xv.y, wv.y, a);
      a = fmaf(xv.z, wv.z, a);
      a = fmaf(xv.w, wv.w, a);
    }
    const int b = bbase + bi;
    if (b < B) out[(long long)b * 75 + o] = fmaf(a, cstd[o], cmean[o]);
  }
}

extern "C" void kernel_launch(void* const* d_in, const int* in_sizes, int n_in,
                              void* d_out, int out_size, void* d_ws, size_t ws_size,
                              hipStream_t stream) {
  const float* points = (const float*)d_in[0];
  const float* color  = (const float*)d_in[1];
  const int*   batch  = (const int*)d_in[2];
  const float* w1  = (const float*)d_in[3];
  const float* b1  = (const float*)d_in[4];
  const float* w2  = (const float*)d_in[5];
  const float* b2  = (const float*)d_in[6];
  const float* w3  = (const float*)d_in[7];
  const float* b3  = (const float*)d_in[8];
  const float* fw1 = (const float*)d_in[9];
  const float* fb1 = (const float*)d_in[10];
  const float* fw2 = (const float*)d_in[11];
  const float* fb2 = (const float*)d_in[12];
  const float* fw3 = (const float*)d_in[13];
  const float* fb3 = (const float*)d_in[14];
  const float* cmean = (const float*)d_in[15];
  const float* cstd  = (const float*)d_in[16];
  float* out = (float*)d_out;

  const int N = in_sizes[2];
  const int B = out_size / 75;

  float* xmax = (float*)d_ws;                                       // [B][256] f32 = 4MB
  unsigned short* w1p = (unsigned short*)((char*)d_ws + 4194304);   // 32x16 bf16
  unsigned short* w2b = (unsigned short*)((char*)d_ws + 4195328);   // 128x32 bf16
  unsigned short* w3b = (unsigned short*)((char*)d_ws + 4203520);   // 256x128 bf16

  hipMemsetAsync(xmax, 0, (size_t)B * 256 * sizeof(float), stream);
  prep_weights<<<128, 256, 0, stream>>>(w1, w2, w3, w1p, w2b, w3b);

  const int nWaves  = (N + 255) / 256;     // 256 points per wave
  const int nBlocks = (nWaves + 3) / 4;
  mlp_segmax_mfma<<<nBlocks, 256, 0, stream>>>(points, color, batch,
                                               w1p, w2b, w3b, b1, b2, b3, xmax, N);

  head_kernel<<<(B + 15) / 16, 256, 0, stream>>>(xmax, fw1, fb1, fw2, fb2, fw3, fb3,
                                                 cmean, cstd, out, B);
}

// Round 4
// 400.096 us; speedup vs baseline: 2.0296x; 2.0296x over previous
//
#include <hip/hip_runtime.h>
#include <hip/hip_bf16.h>

typedef __attribute__((ext_vector_type(8))) short short8;
typedef __attribute__((ext_vector_type(16))) float f32x16;

union U8 { short8 s; unsigned int u[4]; };

static __device__ __forceinline__ unsigned short f2bf(float f) {
  unsigned int u = __float_as_uint(f);
  u += 0x7fffu + ((u >> 16) & 1u);
  return (unsigned short)(u >> 16);
}
// v_cvt_pk_bf16_f32: low half = bf16(lo), high half = bf16(hi), RNE
static __device__ __forceinline__ unsigned int cvtpk(float lo, float hi) {
  unsigned int r;
  asm("v_cvt_pk_bf16_f32 %0, %1, %2" : "=v"(r) : "v"(lo), "v"(hi));
  return r;
}
static __device__ __forceinline__ unsigned int pkrelu(float a, float b) {
  return cvtpk(fmaxf(a, 0.0f), fmaxf(b, 0.0f));
}
static __device__ __forceinline__ f32x16 MFMA(short8 a, short8 b, f32x16 c) {
  return __builtin_amdgcn_mfma_f32_32x32x16_bf16(a, b, c, 0, 0, 0);
}

// ---------------------------------------------------------------------------
// prep: build bf16 weight images in workspace.
//  w1p: [32ch][16k] zero-padded.
//  wimg: fragment-major LDS images. w2 chunks 0..511: ((t2*2+n)*2+g)*32+l31;
//        w3 chunks 512..4607: 512 + ((t*8+k0)*2+g)*32+l31. Each chunk = 16B =
//        the short8 fragment lane l31 reads -> lane-linear => conflict-free.
// ---------------------------------------------------------------------------
__global__ void prep_weights(const float* __restrict__ w1, const float* __restrict__ w2,
                             const float* __restrict__ w3,
                             unsigned short* __restrict__ w1p, uint4* __restrict__ wimg) {
  const int i = blockIdx.x * 256 + threadIdx.x;   // 4096 threads
  if (i < 512) {
    { int c = i >> 4, k = i & 15; w1p[i] = (k < 6) ? f2bf(w1[c * 6 + k]) : (unsigned short)0; }
    const int l31 = i & 31, rest = i >> 5;
    const int g = rest & 1, n = (rest >> 1) & 1, t2 = rest >> 2;
    const float* src = w2 + (l31 + 32 * t2) * 32 + n * 16 + 8 * g;
    uint4 v;
    v.x = (unsigned)f2bf(src[0]) | ((unsigned)f2bf(src[1]) << 16);
    v.y = (unsigned)f2bf(src[2]) | ((unsigned)f2bf(src[3]) << 16);
    v.z = (unsigned)f2bf(src[4]) | ((unsigned)f2bf(src[5]) << 16);
    v.w = (unsigned)f2bf(src[6]) | ((unsigned)f2bf(src[7]) << 16);
    wimg[i] = v;
  }
  if (i < 4096) {
    const int l31 = i & 31, rest = i >> 5;
    const int g = rest & 1, k0 = (rest >> 1) & 7, t = rest >> 4;
    const float* src = w3 + (l31 + 32 * t) * 128 + k0 * 16 + 8 * g;
    uint4 v;
    v.x = (unsigned)f2bf(src[0]) | ((unsigned)f2bf(src[1]) << 16);
    v.y = (unsigned)f2bf(src[2]) | ((unsigned)f2bf(src[3]) << 16);
    v.z = (unsigned)f2bf(src[4]) | ((unsigned)f2bf(src[5]) << 16);
    v.w = (unsigned)f2bf(src[6]) | ((unsigned)f2bf(src[7]) << 16);
    wimg[512 + i] = v;
  }
}

// ---------------------------------------------------------------------------
// Fused per-point MLP (6->32->128->256, bf16 MFMA) + segment-max.
// 8 waves/block; w2+w3 staged ONCE per block in LDS (72KB, fragment-major,
// conflict-free) -> weight cache traffic is O(blocks), not O(waves*subtiles).
// Activations never touch LDS: h1/h2 transposed in-register via cvt_pk +
// shfl_xor(32) half-exchange. Each wave owns 256 contiguous points = 8
// subtiles of 32; L3 gives D[pt][ch] (col=channel) so segment-max is an
// in-lane 16-reg max + one shfl_xor(32) merge; atomicMax only at segment
// transitions, filtered by v>0 (xmax pre-zeroed).
// ---------------------------------------------------------------------------
__global__ __launch_bounds__(512, 4) void mlp_segmax_mfma(
    const float* __restrict__ points, const float* __restrict__ color,
    const int* __restrict__ batch,
    const unsigned short* __restrict__ w1p, const uint4* __restrict__ wimg,
    const float* __restrict__ b1, const float* __restrict__ b2, const float* __restrict__ b3,
    float* __restrict__ xmax, int N)
{
  __shared__ __align__(16) uint4 smem[4608];   // 8KB w2 image + 64KB w3 image
  const int tid  = threadIdx.x;
  const int wv   = tid >> 6;
  const int lane = tid & 63;
  const int g    = lane >> 5;
  const int l31  = lane & 31;

  // ---- stage weight images once per block ----
  for (int i = tid; i < 4608; i += 512) smem[i] = wimg[i];
  __syncthreads();
  const char* w2c = (const char*)smem;
  const char* w3c = (const char*)(smem + 512);

  // small constants held in regs
  const short8 a1 = *reinterpret_cast<const short8*>(w1p + l31 * 16 + 8 * g);
  float b3v[8];
#pragma unroll
  for (int t = 0; t < 8; ++t) b3v[t] = b3[32 * t + l31];

  const int wid = blockIdx.x * 8 + wv;
  const long long wbase = (long long)wid * 256;
  int cur = -1;
  float rmax[8];
#pragma unroll
  for (int t = 0; t < 8; ++t) rmax[t] = -INFINITY;

  auto flush = [&]() {
    if (cur < 0) return;
#pragma unroll
    for (int t = 0; t < 8; ++t) {
      float v = fmaxf(rmax[t], __shfl_xor(rmax[t], 32));
      if (lane < 32 && v > 0.0f)
        atomicMax((int*)xmax + cur * 256 + 32 * t + lane, __float_as_int(v));
    }
  };

  // ---- input prefetch for subtile 0 ----
  float n0 = 0, n1 = 0, n2 = 0, n3 = 0, n4 = 0, n5 = 0;
  int nseg = -2 - lane;
  if (wbase < (long long)N) {
    const int p = (int)wbase + l31;
    n0 = points[p * 3 + 0]; n1 = points[p * 3 + 1]; n2 = points[p * 3 + 2];
    n3 = color[p * 3 + 0];  n4 = color[p * 3 + 1];  n5 = color[p * 3 + 2];
    nseg = batch[p];
  }

  for (int it = 0; it < 8; ++it) {
    const long long base = wbase + (long long)it * 32;
    if (base >= (long long)N) break;   // N % 32 == 0 for this problem

    const float c0 = n0, c1 = n1, c2 = n2, c3 = n3, c4 = n4, c5 = n5;
    const int segv = nseg;
    if (base + 32 < (long long)N && it < 7) {
      const int p = (int)base + 32 + l31;
      n0 = points[p * 3 + 0]; n1 = points[p * 3 + 1]; n2 = points[p * 3 + 2];
      n3 = color[p * 3 + 0];  n4 = color[p * 3 + 1];  n5 = color[p * 3 + 2];
      nseg = batch[p];
    }

    // opaque per-iteration handles: keep bias loads + LDS reads inside the loop
    unsigned long long b1a = (unsigned long long)b1; asm volatile("" : "+s"(b1a));
    unsigned long long b2a = (unsigned long long)b2; asm volatile("" : "+s"(b2a));
    const float* b1l = (const float*)b1a;
    const float* b2l = (const float*)b2a;
    int z = 0; asm volatile("" : "+v"(z));   // opaque 0 for LDS offsets

    // ---------------- layer 1 (6->32): D[ch][pt] ----------------
    const unsigned int zm = (g == 0) ? 0xffffffffu : 0u;  // g=1 lanes = K-pad
    U8 bin;
    bin.u[0] = cvtpk(c0, c1) & zm;
    bin.u[1] = cvtpk(c2, c3) & zm;
    bin.u[2] = cvtpk(c4, c5) & zm;
    bin.u[3] = 0;
    f32x16 ci;
#pragma unroll
    for (int q = 0; q < 4; ++q) {
      const float4 bv = *reinterpret_cast<const float4*>(b1l + 8 * q + 4 * g);
      ci[4 * q + 0] = bv.x; ci[4 * q + 1] = bv.y; ci[4 * q + 2] = bv.z; ci[4 * q + 3] = bv.w;
    }
    f32x16 d1 = MFMA(a1, bin.s, ci);

    // relu+pack h1, then half-wave exchange to build B-fragments h1f[n]
    unsigned int W1[4][2];
#pragma unroll
    for (int q = 0; q < 4; ++q) {
      W1[q][0] = pkrelu(d1[4 * q + 0], d1[4 * q + 1]);
      W1[q][1] = pkrelu(d1[4 * q + 2], d1[4 * q + 3]);
    }
    U8 h1f[2];
#pragma unroll
    for (int n = 0; n < 2; ++n) {
      unsigned int r0 = __shfl_xor(W1[2 * n + 1 - g][0], 32);
      unsigned int r1 = __shfl_xor(W1[2 * n + 1 - g][1], 32);
      // words 0,1 = k-src half 0; words 2,3 = k-src half 1 (own q = 2n+g)
      h1f[n].u[0] = (g == 0) ? W1[2 * n + g][0] : r0;
      h1f[n].u[1] = (g == 0) ? W1[2 * n + g][1] : r1;
      h1f[n].u[2] = (g == 1) ? W1[2 * n + g][0] : r0;
      h1f[n].u[3] = (g == 1) ? W1[2 * n + g][1] : r1;
    }

    // ---------------- layer 2 (32->128): D[ch][pt] per 32-ch tile ----------------
    unsigned int own2[4][2][2], rc2[4][2][2];
#pragma unroll
    for (int t2 = 0; t2 < 4; ++t2) {
      f32x16 cc;
#pragma unroll
      for (int q = 0; q < 4; ++q) {
        const float4 bv = *reinterpret_cast<const float4*>(b2l + 32 * t2 + 8 * q + 4 * g);
        cc[4 * q + 0] = bv.x; cc[4 * q + 1] = bv.y; cc[4 * q + 2] = bv.z; cc[4 * q + 3] = bv.w;
      }
      const short8 a20 = *reinterpret_cast<const short8*>(
          w2c + ((((t2 * 2 + 0) * 2 + g) * 32 + l31) << 4) + z);
      const short8 a21 = *reinterpret_cast<const short8*>(
          w2c + ((((t2 * 2 + 1) * 2 + g) * 32 + l31) << 4) + z);
      f32x16 d2 = MFMA(a20, h1f[0].s, cc);
      d2 = MFMA(a21, h1f[1].s, d2);
      unsigned int Wt[4][2];
#pragma unroll
      for (int q = 0; q < 4; ++q) {
        Wt[q][0] = pkrelu(d2[4 * q + 0], d2[4 * q + 1]);
        Wt[q][1] = pkrelu(d2[4 * q + 2], d2[4 * q + 3]);
      }
#pragma unroll
      for (int m = 0; m < 2; ++m) {
        own2[t2][m][0] = Wt[2 * m + g][0];
        own2[t2][m][1] = Wt[2 * m + g][1];
        rc2[t2][m][0] = __shfl_xor(Wt[2 * m + 1 - g][0], 32);
        rc2[t2][m][1] = __shfl_xor(Wt[2 * m + 1 - g][1], 32);
      }
    }
    // build L3 A-fragments: a3[k0] = h2[pt=l31][c=16*k0+8g+j]
    U8 a3[8];
#pragma unroll
    for (int k0 = 0; k0 < 8; ++k0) {
      const int t2 = k0 >> 1, m = k0 & 1;
      a3[k0].u[0] = (g == 0) ? own2[t2][m][0] : rc2[t2][m][0];
      a3[k0].u[1] = (g == 0) ? own2[t2][m][1] : rc2[t2][m][1];
      a3[k0].u[2] = (g == 1) ? own2[t2][m][0] : rc2[t2][m][0];
      a3[k0].u[3] = (g == 1) ? own2[t2][m][1] : rc2[t2][m][1];
    }

    // ---------------- segment bookkeeping ----------------
    const int segA = __builtin_amdgcn_readfirstlane(segv);
    const int segD = __shfl(segv, 31);
    const bool caseU = (segA == segD);
    if (segA != cur) {
      flush();
#pragma unroll
      for (int t = 0; t < 8; ++t) rmax[t] = -INFINITY;
      cur = segA;
    }
    unsigned int bA = 0, bD = 0;
    bool restAny = false;
    if (!caseU) {
      bA = (unsigned int)__ballot(segv == segA);
      bD = (unsigned int)__ballot(segv == segD);
      restAny = ((bA | bD) != 0xffffffffu);
    }

    // ---------------- layer 3 (128->256): D[pt][ch], col=channel ----------------
#pragma unroll
    for (int t = 0; t < 8; ++t) {
      f32x16 acc;
#pragma unroll
      for (int r = 0; r < 16; ++r) acc[r] = b3v[t];
#pragma unroll
      for (int k0 = 0; k0 < 8; ++k0) {
        const short8 bf = *reinterpret_cast<const short8*>(
            w3c + ((((t * 8 + k0) * 2 + g) * 32 + l31) << 4) + z);
        acc = MFMA(a3[k0].s, bf, acc);
      }
      if (caseU) {
        float m = acc[0];
#pragma unroll
        for (int r = 1; r < 16; ++r) m = fmaxf(m, acc[r]);
        rmax[t] = fmaxf(rmax[t], m);
      } else {
        float ma = -INFINITY, md = -INFINITY;
#pragma unroll
        for (int r = 0; r < 16; ++r) {
          const int idx = (r & 3) + 8 * (r >> 2) + 4 * g;
          const unsigned int bit = 1u << idx;
          const float v = acc[r];
          ma = fmaxf(ma, (bA & bit) ? v : -INFINITY);
          md = fmaxf(md, (bD & bit) ? v : -INFINITY);
        }
        if (restAny) {   // >2 segments inside one 32-pt subtile: rare slow path
#pragma unroll
          for (int r = 0; r < 16; ++r) {
            const int idx = (r & 3) + 8 * (r >> 2) + 4 * g;
            const unsigned int bit = 1u << idx;
            if (!((bA | bD) & bit)) {
              const int sid = __shfl(segv, idx);
              const float v = acc[r];
              if (sid >= 0 && v > 0.0f)
                atomicMax((int*)xmax + sid * 256 + 32 * t + l31, __float_as_int(v));
            }
          }
        }
        float va = fmaxf(rmax[t], ma);
        va = fmaxf(va, __shfl_xor(va, 32));
        if (lane < 32 && va > 0.0f)
          atomicMax((int*)xmax + segA * 256 + 32 * t + l31, __float_as_int(va));
        rmax[t] = md;    // start accumulating segD
      }
    }
    if (!caseU) cur = segD;
  }
  flush();
}

// ---------------------------------------------------------------------------
// FC head  [B,256] -> 128 -> 64 -> 75, + coef scale/shift (unchanged)
// ---------------------------------------------------------------------------
__global__ __launch_bounds__(256) void head_kernel(
    const float* __restrict__ xmax,
    const float* __restrict__ fw1, const float* __restrict__ fb1,
    const float* __restrict__ fw2, const float* __restrict__ fb2,
    const float* __restrict__ fw3, const float* __restrict__ fb3,
    const float* __restrict__ cmean, const float* __restrict__ cstd,
    float* __restrict__ out, int B)
{
  __shared__ __align__(16) float xm[16][260];
  __shared__ __align__(16) float h1b[16][132];
  __shared__ __align__(16) float h2b[16][68];

  const int t = threadIdx.x;
  const int bbase = blockIdx.x * 16;

  for (int i = t; i < 16 * 256; i += 256) {
    const int bi = i >> 8, k = i & 255;
    const int bb = min(bbase + bi, B - 1);
    xm[bi][k] = xmax[(long long)bb * 256 + k];
  }
  __syncthreads();

  {
    const int bi = t >> 4, oi = t & 15;
    float acc[8];
#pragma unroll
    for (int u = 0; u < 8; ++u) acc[u] = fb1[oi * 8 + u];
    for (int k = 0; k < 256; k += 4) {
      const float4 xv = *reinterpret_cast<const float4*>(&xm[bi][k]);
#pragma unroll
      for (int u = 0; u < 8; ++u) {
        const float4 wv = *reinterpret_cast<const float4*>(fw1 + (oi * 8 + u) * 256 + k);
        acc[u] = fmaf(xv.x, wv.x, acc[u]);
        acc[u] = fmaf(xv.y, wv.y, acc[u]);
        acc[u] = fmaf(xv.z, wv.z, acc[u]);
        acc[u] = fmaf(xv.w, wv.w, acc[u]);
      }
    }
#pragma unroll
    for (int u = 0; u < 8; ++u) h1b[bi][oi * 8 + u] = fmaxf(acc[u], 0.0f);
  }
  __syncthreads();

  {
    const int bi = t >> 4, oi = t & 15;
    float acc[4];
#pragma unroll
    for (int u = 0; u < 4; ++u) acc[u] = fb2[oi * 4 + u];
    for (int k = 0; k < 128; k += 4) {
      const float4 xv = *reinterpret_cast<const float4*>(&h1b[bi][k]);
#pragma unroll
      for (int u = 0; u < 4; ++u) {
        const float4 wv = *reinterpret_cast<const float4*>(fw2 + (oi * 4 + u) * 128 + k);
        acc[u] = fmaf(xv.x, wv.x, acc[u]);
        acc[u] = fmaf(xv.y, wv.y, acc[u]);
        acc[u] = fmaf(xv.z, wv.z, acc[u]);
        acc[u] = fmaf(xv.w, wv.w, acc[u]);
      }
    }
#pragma unroll
    for (int u = 0; u < 4; ++u) h2b[bi][oi * 4 + u] = fmaxf(acc[u], 0.0f);
  }
  __syncthreads();

  for (int i = t; i < 16 * 75; i += 256) {
    const int bi = i / 75, o = i - bi * 75;
    float a = fb3[o];
    for (int k = 0; k < 64; k += 4) {
      const float4 xv = *reinterpret_cast<const float4*>(&h2b[bi][k]);
      const float4 wv = *reinterpret_cast<const float4*>(fw3 + o * 64 + k);
      a = fmaf(xv.x, wv.x, a);
      a = fmaf(xv.y, wv.y, a);
      a = fmaf(xv.z, wv.z, a);
      a = fmaf(xv.w, wv.w, a);
    }
    const int b = bbase + bi;
    if (b < B) out[(long long)b * 75 + o] = fmaf(a, cstd[o], cmean[o]);
  }
}

extern "C" void kernel_launch(void* const* d_in, const int* in_sizes, int n_in,
                              void* d_out, int out_size, void* d_ws, size_t ws_size,
                              hipStream_t stream) {
  const float* points = (const float*)d_in[0];
  const float* color  = (const float*)d_in[1];
  const int*   batch  = (const int*)d_in[2];
  const float* w1  = (const float*)d_in[3];
  const float* b1  = (const float*)d_in[4];
  const float* w2  = (const float*)d_in[5];
  const float* b2  = (const float*)d_in[6];
  const float* w3  = (const float*)d_in[7];
  const float* b3  = (const float*)d_in[8];
  const float* fw1 = (const float*)d_in[9];
  const float* fb1 = (const float*)d_in[10];
  const float* fw2 = (const float*)d_in[11];
  const float* fb2 = (const float*)d_in[12];
  const float* fw3 = (const float*)d_in[13];
  const float* fb3 = (const float*)d_in[14];
  const float* cmean = (const float*)d_in[15];
  const float* cstd  = (const float*)d_in[16];
  float* out = (float*)d_out;

  const int N = in_sizes[2];
  const int B = out_size / 75;

  float* xmax = (float*)d_ws;                                       // [B][256] f32 = 4MB
  unsigned short* w1p = (unsigned short*)((char*)d_ws + 4194304);   // 1KB
  uint4* wimg = (uint4*)((char*)d_ws + 4198400);                    // 72KB images

  hipMemsetAsync(xmax, 0, (size_t)B * 256 * sizeof(float), stream);
  prep_weights<<<16, 256, 0, stream>>>(w1, w2, w3, w1p, wimg);

  const int nBlocks = (N + 2047) / 2048;   // 8 waves x 256 pts per block
  mlp_segmax_mfma<<<nBlocks, 512, 0, stream>>>(points, color, batch,
                                               w1p, wimg, b1, b2, b3, xmax, N);

  head_kernel<<<(B + 15) / 16, 256, 0, stream>>>(xmax, fw1, fb1, fw2, fb2, fw3, fb3,
                                                 cmean, cstd, out, B);
}